// Round 4
// baseline (186.993 us; speedup 1.0000x reference)
//
#include <hip/hip_runtime.h>

typedef __bf16 bf16;
typedef __attribute__((ext_vector_type(8))) __bf16 bf16x8;
typedef __attribute__((ext_vector_type(4))) __bf16 bf16x4;
typedef __attribute__((ext_vector_type(4))) float f32x4;

constexpr int Bb = 8;
constexpr int Ss = 1024;
constexpr int Ee = 128;
constexpr int Hh = 8;
constexpr int Dd = 128;
constexpr int HD = 1024;

// async 16B global -> LDS (wave-uniform LDS base + lane*16, per-lane global src)
__device__ __forceinline__ void gl_lds16(const bf16* gp, bf16* lp) {
    __builtin_amdgcn_global_load_lds(
        (const __attribute__((address_space(1))) unsigned int*)gp,
        (__attribute__((address_space(3))) unsigned int*)lp, 16, 0, 0);
}

// ---------------------------------------------------------------------------
// K0: fp32 -> bf16 convert of Wq, Wk, Wv.  Wq gets log2(e)/sqrt(128) folded.
// ---------------------------------------------------------------------------
__global__ void k_cvt(const float* __restrict__ Wq, const float* __restrict__ Wk,
                      const float* __restrict__ Wv,
                      bf16* __restrict__ Wqb, bf16* __restrict__ Wkb, bf16* __restrict__ Wvb)
{
    int gid = blockIdx.x * 256 + threadIdx.x;
    const float* src; bf16* dst; int off; float s = 1.0f;
    if      (gid < 32768) { src = Wq; dst = Wqb; off = gid;         s = 0.12751741530603157f; }
    else if (gid < 65536) { src = Wk; dst = Wkb; off = gid - 32768; }
    else                  { src = Wv; dst = Wvb; off = gid - 65536; }
    float4 f = ((const float4*)src)[off];
    bf16x4 p;
    p[0] = (bf16)(f.x * s); p[1] = (bf16)(f.y * s);
    p[2] = (bf16)(f.z * s); p[3] = (bf16)(f.w * s);
    ((bf16x4*)dst)[off] = p;
}

// ---------------------------------------------------------------------------
// K1: QKV projection (unchanged from R3).  Q/K -> [b,h,s,d]; V -> [b,h,d,s].
// ---------------------------------------------------------------------------
__global__ __launch_bounds__(256, 2) void k_qkv(
    const float* __restrict__ qin, const float* __restrict__ kin, const float* __restrict__ vin,
    const bf16* __restrict__ Wqb, const bf16* __restrict__ Wkb, const bf16* __restrict__ Wvb,
    bf16* __restrict__ Qh, bf16* __restrict__ Kh, bf16* __restrict__ Vt)
{
    const int rb    = blockIdx.x;
    const int h     = blockIdx.y;
    const int which = blockIdx.z;
    const float* x = (which == 0) ? qin : (which == 1) ? kin : vin;
    const bf16*  W = (which == 0) ? Wqb : (which == 1) ? Wkb : Wvb;

    __shared__ bf16 Xs[128][136];
    __shared__ bf16 Ws[128][136];

    const int tid  = threadIdx.x;
    const int wv   = tid >> 6;
    const int lane = tid & 63;
    const int lo   = lane & 15;
    const int q4   = lane >> 4;

#pragma unroll
    for (int t = 0; t < 8; ++t) {
        int c = tid + t * 256;
        int row = c >> 4, c8 = (c & 15) << 3;
        const float* xp = &x[(rb * 128 + row) * Ee + c8];
        float4 f0 = *(const float4*)xp;
        float4 f1 = *(const float4*)(xp + 4);
        bf16x8 p;
        p[0] = (bf16)f0.x; p[1] = (bf16)f0.y; p[2] = (bf16)f0.z; p[3] = (bf16)f0.w;
        p[4] = (bf16)f1.x; p[5] = (bf16)f1.y; p[6] = (bf16)f1.z; p[7] = (bf16)f1.w;
        *(bf16x8*)&Xs[row][c8] = p;
        *(bf16x8*)&Ws[row][c8] = *(const bf16x8*)&W[(h * 128 + row) * Ee + c8];
    }
    __syncthreads();

    const bf16 (*Ap)[136] = (which == 2) ? Ws : Xs;
    const bf16 (*Bp)[136] = (which == 2) ? Xs : Ws;

    f32x4 acc[2][8];
#pragma unroll
    for (int i = 0; i < 2; ++i)
#pragma unroll
        for (int j = 0; j < 8; ++j) acc[i][j] = f32x4{0.f, 0.f, 0.f, 0.f};

#pragma unroll
    for (int kq = 0; kq < 4; ++kq) {
        bf16x8 a[2], b8[8];
#pragma unroll
        for (int ri = 0; ri < 2; ++ri)
            a[ri] = *(const bf16x8*)&Ap[wv * 32 + ri * 16 + lo][kq * 32 + q4 * 8];
#pragma unroll
        for (int cj = 0; cj < 8; ++cj)
            b8[cj] = *(const bf16x8*)&Bp[cj * 16 + lo][kq * 32 + q4 * 8];
#pragma unroll
        for (int ri = 0; ri < 2; ++ri)
#pragma unroll
            for (int cj = 0; cj < 8; ++cj)
                acc[ri][cj] = __builtin_amdgcn_mfma_f32_16x16x32_bf16(
                    a[ri], b8[cj], acc[ri][cj], 0, 0, 0);
    }

    const int bb = rb >> 3;
    const int s0 = (rb & 7) * 128;
    if (which < 2) {
        bf16* dst = ((which == 0) ? Qh : Kh) + (bb * Hh + h) * Ss * Dd;
#pragma unroll
        for (int ri = 0; ri < 2; ++ri)
#pragma unroll
            for (int cj = 0; cj < 8; ++cj)
#pragma unroll
                for (int r = 0; r < 4; ++r) {
                    int row = wv * 32 + ri * 16 + q4 * 4 + r;
                    int col = cj * 16 + lo;
                    dst[(s0 + row) * Dd + col] = (bf16)acc[ri][cj][r];
                }
    } else {
        bf16* dst = Vt + (bb * Hh + h) * Dd * Ss;
#pragma unroll
        for (int ri = 0; ri < 2; ++ri)
#pragma unroll
            for (int cj = 0; cj < 8; ++cj)
#pragma unroll
                for (int r = 0; r < 4; ++r) {
                    int row = wv * 32 + ri * 16 + q4 * 4 + r;   // d
                    int col = cj * 16 + lo;                     // s-local
                    dst[row * Ss + s0 + col] = (bf16)acc[ri][cj][r];
                }
    }
}

// ---------------------------------------------------------------------------
// K2: streaming attention, P-in-register (no LDS round-trip).
//   S^T = K·Q^T via mfma(A=kf, B=qf)  ->  C-layout S^T[key'][qrow]
//   K-tile staged with key-row permutation: LDS row t*16+q4*4+r holds real key
//   8*q4+4*t+r (per 32-block), so two 16-row C-tiles concatenate into the
//   bf16x8 B-fragment (k=q4*8+j) of the PV mfma:
//   O^T[d][qrow] += mfma(A=V^T-frag, B=exp2(S^T + mask)-frag).
//   Unnormalized exp2 softmax; row-sum is lane-local + 2 shuffles at end.
// block 256 = 4 waves (32 qrows each); grid (64 bh, 8 qt); 3 blocks/CU.
// ---------------------------------------------------------------------------
__global__ __launch_bounds__(256, 3) void k_attn(
    const bf16* __restrict__ Qh, const bf16* __restrict__ Kh, const bf16* __restrict__ Vt,
    const float* __restrict__ mask, bf16* __restrict__ oc)
{
    const int bh = blockIdx.x;
    const int qt = blockIdx.y;
    const int b  = bh >> 3;
    const int h  = bh & 7;
    const int tid  = threadIdx.x;
    const int wv   = tid >> 6;     // 0..3
    const int lane = tid & 63;
    const int lo   = lane & 15;
    const int q4   = lane >> 4;

    __shared__ bf16 KsL[64 * 128];   // [key' permuted][d-chunk swizzled]
    __shared__ bf16 VsL[128 * 64];   // [d][key-chunk swizzled]
    __shared__ float maskS[1024];    // pre-scaled by log2(e), real-key indexed

    const bf16* Qb = Qh + bh * Ss * Dd;
    const bf16* Kb = Kh + bh * Ss * Dd;
    const bf16* Vb = Vt + bh * Dd * Ss;

#pragma unroll
    for (int t = 0; t < 4; ++t)
        maskS[tid + t * 256] = mask[b * Ss + tid + t * 256] * 1.4426950408889634f;

    // Q fragments (pre-scaled by log2e/sqrt(d)): B-operand of QK.
    // lane holds Q[qrow = q0+nt*16+lo][d = kq*32+q4*8+j]
    const int q0 = qt * 128 + wv * 32;
    bf16x8 qf[2][4];
#pragma unroll
    for (int nt = 0; nt < 2; ++nt)
#pragma unroll
        for (int kq = 0; kq < 4; ++kq)
            qf[nt][kq] = *(const bf16x8*)&Qb[(q0 + nt * 16 + lo) * Dd + kq * 32 + q4 * 8];

    f32x4 accO[8][2];                // O^T[d-tile dm][qrow-tile nt]
#pragma unroll
    for (int dm = 0; dm < 8; ++dm)
#pragma unroll
        for (int nt = 0; nt < 2; ++nt) accO[dm][nt] = f32x4{0.f, 0.f, 0.f, 0.f};
    float lsum[2] = {0.f, 0.f};

    const int sw = lo & 7;   // read-side chunk swizzle key

    for (int kt = 0; kt < 16; ++kt) {
        const int j0 = kt * 64;
        // stage K tile: LDS row r' gets real key keyperm(r'); chunk-swizzled.
        // keyperm(r') = (r'&32) + 8*((r'>>2)&3) + 4*((r'>>4)&1) + (r'&3)
#pragma unroll
        for (int t = 0; t < 4; ++t) {
            int i = wv * 4 + t;
            int row = i * 4 + (lane >> 4);        // LDS row r'
            int grow = (row & 32) + (((row >> 2) & 3) << 3)
                     + (((row >> 4) & 1) << 2) + (row & 3);
            int g = (lane & 15) ^ (row & 7);
            gl_lds16(Kb + (j0 + grow) * Dd + g * 8, &KsL[i * 512]);
        }
        // stage V^T tile 128x64 (natural key order, chunk-swizzled)
#pragma unroll
        for (int t = 0; t < 4; ++t) {
            int i = wv * 4 + t;
            int row = i * 8 + (lane >> 3);
            int g = (lane & 7) ^ (row & 7);
            gl_lds16(Vb + row * Ss + j0 + g * 8, &VsL[i * 512]);
        }
        __syncthreads();

        // QK: S^T[key'][qrow], 4 key'-tiles x 2 qrow-tiles
        f32x4 sc[4][2];
#pragma unroll
        for (int c = 0; c < 4; ++c)
#pragma unroll
            for (int nt = 0; nt < 2; ++nt) sc[c][nt] = f32x4{0.f, 0.f, 0.f, 0.f};
#pragma unroll
        for (int kq = 0; kq < 4; ++kq) {
            bf16x8 kf[4];
#pragma unroll
            for (int c = 0; c < 4; ++c)
                kf[c] = *(const bf16x8*)&KsL[(c * 16 + lo) * 128 + (((kq << 2) + q4) ^ sw) * 8];
#pragma unroll
            for (int c = 0; c < 4; ++c)
#pragma unroll
                for (int nt = 0; nt < 2; ++nt)
                    sc[c][nt] = __builtin_amdgcn_mfma_f32_16x16x32_bf16(
                        kf[c], qf[nt][kq], sc[c][nt], 0, 0, 0);
        }

        // exp2 + pack straight into PV B-fragments.
        // C-tile c=kb*2+t reg r holds real key j0+kb*32+q4*8+t*4+r at qrow nt*16+lo.
        bf16x8 p8[2][2];   // [kb][nt]
#pragma unroll
        for (int kb = 0; kb < 2; ++kb) {
#pragma unroll
            for (int t = 0; t < 2; ++t) {
                const float4 mv = *(const float4*)&maskS[j0 + kb * 32 + q4 * 8 + t * 4];
                const int c = kb * 2 + t;
#pragma unroll
                for (int nt = 0; nt < 2; ++nt) {
                    float e0 = exp2f(sc[c][nt][0] + mv.x);
                    float e1 = exp2f(sc[c][nt][1] + mv.y);
                    float e2 = exp2f(sc[c][nt][2] + mv.z);
                    float e3 = exp2f(sc[c][nt][3] + mv.w);
                    lsum[nt] += (e0 + e1) + (e2 + e3);
                    p8[kb][nt][t * 4 + 0] = (bf16)e0;
                    p8[kb][nt][t * 4 + 1] = (bf16)e1;
                    p8[kb][nt][t * 4 + 2] = (bf16)e2;
                    p8[kb][nt][t * 4 + 3] = (bf16)e3;
                }
            }
        }

        // PV: O^T[d][qrow] += V^T-frag · P-frag   (A m=d, B k=key n=qrow)
#pragma unroll
        for (int kb = 0; kb < 2; ++kb)
#pragma unroll
            for (int dm = 0; dm < 8; ++dm) {
                bf16x8 vf = *(const bf16x8*)&VsL[(dm * 16 + lo) * 64 + (((kb << 2) + q4) ^ sw) * 8];
#pragma unroll
                for (int nt = 0; nt < 2; ++nt)
                    accO[dm][nt] = __builtin_amdgcn_mfma_f32_16x16x32_bf16(
                        vf, p8[kb][nt], accO[dm][nt], 0, 0, 0);
            }
        __syncthreads();   // protect KsL/VsL before next staging
    }

    // epilogue: full row sums (reduce over q4 quads), normalize, store O.
    // lane holds O^T[dm*16+q4*4+r][qrow=nt*16+lo]
#pragma unroll
    for (int nt = 0; nt < 2; ++nt) {
        float s = lsum[nt];
        s += __shfl_xor(s, 16, 64);
        s += __shfl_xor(s, 32, 64);
        float inv = 1.0f / (s + 1e-12f);
        int sg = q0 + nt * 16 + lo;
        bf16* dst = oc + (b * Ss + sg) * HD + h * 128;
#pragma unroll
        for (int dm = 0; dm < 8; ++dm) {
            bf16x4 o;
#pragma unroll
            for (int r = 0; r < 4; ++r) o[r] = (bf16)(accO[dm][nt][r] * inv);
            *(bf16x4*)&dst[dm * 16 + q4 * 4] = o;
        }
    }
}

// ---------------------------------------------------------------------------
// K3: output projection + bias, streaming (unchanged from R3).
// ---------------------------------------------------------------------------
__global__ __launch_bounds__(256, 4) void k_proj(
    const bf16* __restrict__ oc, const float* __restrict__ Wc,
    const float* __restrict__ bc, float* __restrict__ out)
{
    const int mt   = blockIdx.x;
    const int tid  = threadIdx.x;
    const int wv   = tid >> 6;
    const int lane = tid & 63;
    const int lo   = lane & 15;
    const int q4   = lane >> 4;

    f32x4 acc[2];
    acc[0] = f32x4{0.f, 0.f, 0.f, 0.f};
    acc[1] = f32x4{0.f, 0.f, 0.f, 0.f};

    const bf16* arow = oc + (mt * 16 + lo) * HD + q4 * 8;

    for (int kc = 0; kc < 8; ++kc) {
        const int k0 = kc * 128;
        bf16x8 a[4];
#pragma unroll
        for (int kq = 0; kq < 4; ++kq)
            a[kq] = *(const bf16x8*)&arow[k0 + kq * 32];
#pragma unroll
        for (int cj = 0; cj < 2; ++cj) {
            const int n = wv * 32 + cj * 16 + lo;
#pragma unroll
            for (int kq = 0; kq < 4; ++kq) {
                const float* wp = &Wc[n * HD + k0 + kq * 32 + q4 * 8];
                float4 f0 = *(const float4*)wp;
                float4 f1 = *(const float4*)(wp + 4);
                bf16x8 bfr;
                bfr[0] = (bf16)f0.x; bfr[1] = (bf16)f0.y; bfr[2] = (bf16)f0.z; bfr[3] = (bf16)f0.w;
                bfr[4] = (bf16)f1.x; bfr[5] = (bf16)f1.y; bfr[6] = (bf16)f1.z; bfr[7] = (bf16)f1.w;
                acc[cj] = __builtin_amdgcn_mfma_f32_16x16x32_bf16(
                    a[kq], bfr, acc[cj], 0, 0, 0);
            }
        }
    }

#pragma unroll
    for (int cj = 0; cj < 2; ++cj) {
        int col = wv * 32 + cj * 16 + lo;
        float bias = bc[col];
#pragma unroll
        for (int r = 0; r < 4; ++r) {
            int row = mt * 16 + q4 * 4 + r;
            out[row * Ee + col] = acc[cj][r] + bias;
        }
    }
}

// ---------------------------------------------------------------------------
extern "C" void kernel_launch(void* const* d_in, const int* in_sizes, int n_in,
                              void* d_out, int out_size, void* d_ws, size_t ws_size,
                              hipStream_t stream)
{
    const float* q    = (const float*)d_in[0];
    const float* k    = (const float*)d_in[1];
    const float* v    = (const float*)d_in[2];
    const float* mask = (const float*)d_in[3];
    const float* Wq   = (const float*)d_in[4];
    const float* Wk   = (const float*)d_in[5];
    const float* Wv   = (const float*)d_in[6];
    const float* Wc   = (const float*)d_in[7];
    const float* bc   = (const float*)d_in[8];
    float* out = (float*)d_out;

    constexpr int NBH = Bb * Hh * Ss * Dd;   // 8388608
    bf16* Qh = (bf16*)d_ws;
    bf16* Kh = Qh + NBH;
    bf16* Vt = Kh + NBH;
    bf16* oc = Vt + NBH;
    bf16* Wqb = oc;                          // aliased, dead before k_attn
    bf16* Wkb = Wqb + HD * Ee;
    bf16* Wvb = Wkb + HD * Ee;

    k_cvt<<<dim3(384), 256, 0, stream>>>(Wq, Wk, Wv, Wqb, Wkb, Wvb);
    k_qkv<<<dim3(64, 8, 3), 256, 0, stream>>>(q, k, v, Wqb, Wkb, Wvb, Qh, Kh, Vt);
    k_attn<<<dim3(64, 8), 256, 0, stream>>>(Qh, Kh, Vt, mask, oc);
    k_proj<<<dim3(512), 256, 0, stream>>>(oc, Wc, bc, out);
}

// Round 5
// 178.370 us; speedup vs baseline: 1.0483x; 1.0483x over previous
//
#include <hip/hip_runtime.h>

typedef __bf16 bf16;
typedef __attribute__((ext_vector_type(8))) __bf16 bf16x8;
typedef __attribute__((ext_vector_type(4))) __bf16 bf16x4;
typedef __attribute__((ext_vector_type(4))) float f32x4;

constexpr int Bb = 8;
constexpr int Ss = 1024;
constexpr int Ee = 128;
constexpr int Hh = 8;
constexpr int Dd = 128;
constexpr int HD = 1024;

// async 16B global -> LDS (wave-uniform LDS base + lane*16, per-lane global src)
__device__ __forceinline__ void gl_lds16(const bf16* gp, bf16* lp) {
    __builtin_amdgcn_global_load_lds(
        (const __attribute__((address_space(1))) unsigned int*)gp,
        (__attribute__((address_space(3))) unsigned int*)lp, 16, 0, 0);
}

// ---------------------------------------------------------------------------
// K0: fp32 -> bf16 convert of Wq, Wk, Wv.  Wq gets log2(e)/sqrt(128) folded.
// ---------------------------------------------------------------------------
__global__ void k_cvt(const float* __restrict__ Wq, const float* __restrict__ Wk,
                      const float* __restrict__ Wv,
                      bf16* __restrict__ Wqb, bf16* __restrict__ Wkb, bf16* __restrict__ Wvb)
{
    int gid = blockIdx.x * 256 + threadIdx.x;
    const float* src; bf16* dst; int off; float s = 1.0f;
    if      (gid < 32768) { src = Wq; dst = Wqb; off = gid;         s = 0.12751741530603157f; }
    else if (gid < 65536) { src = Wk; dst = Wkb; off = gid - 32768; }
    else                  { src = Wv; dst = Wvb; off = gid - 65536; }
    float4 f = ((const float4*)src)[off];
    bf16x4 p;
    p[0] = (bf16)(f.x * s); p[1] = (bf16)(f.y * s);
    p[2] = (bf16)(f.z * s); p[3] = (bf16)(f.w * s);
    ((bf16x4*)dst)[off] = p;
}

// ---------------------------------------------------------------------------
// K1: QKV projection (unchanged).  Q/K -> [b,h,s,d]; V -> [b,h,d,s].
// ---------------------------------------------------------------------------
__global__ __launch_bounds__(256, 2) void k_qkv(
    const float* __restrict__ qin, const float* __restrict__ kin, const float* __restrict__ vin,
    const bf16* __restrict__ Wqb, const bf16* __restrict__ Wkb, const bf16* __restrict__ Wvb,
    bf16* __restrict__ Qh, bf16* __restrict__ Kh, bf16* __restrict__ Vt)
{
    const int rb    = blockIdx.x;
    const int h     = blockIdx.y;
    const int which = blockIdx.z;
    const float* x = (which == 0) ? qin : (which == 1) ? kin : vin;
    const bf16*  W = (which == 0) ? Wqb : (which == 1) ? Wkb : Wvb;

    __shared__ bf16 Xs[128][136];
    __shared__ bf16 Ws[128][136];

    const int tid  = threadIdx.x;
    const int wv   = tid >> 6;
    const int lane = tid & 63;
    const int lo   = lane & 15;
    const int q4   = lane >> 4;

#pragma unroll
    for (int t = 0; t < 8; ++t) {
        int c = tid + t * 256;
        int row = c >> 4, c8 = (c & 15) << 3;
        const float* xp = &x[(rb * 128 + row) * Ee + c8];
        float4 f0 = *(const float4*)xp;
        float4 f1 = *(const float4*)(xp + 4);
        bf16x8 p;
        p[0] = (bf16)f0.x; p[1] = (bf16)f0.y; p[2] = (bf16)f0.z; p[3] = (bf16)f0.w;
        p[4] = (bf16)f1.x; p[5] = (bf16)f1.y; p[6] = (bf16)f1.z; p[7] = (bf16)f1.w;
        *(bf16x8*)&Xs[row][c8] = p;
        *(bf16x8*)&Ws[row][c8] = *(const bf16x8*)&W[(h * 128 + row) * Ee + c8];
    }
    __syncthreads();

    const bf16 (*Ap)[136] = (which == 2) ? Ws : Xs;
    const bf16 (*Bp)[136] = (which == 2) ? Xs : Ws;

    f32x4 acc[2][8];
#pragma unroll
    for (int i = 0; i < 2; ++i)
#pragma unroll
        for (int j = 0; j < 8; ++j) acc[i][j] = f32x4{0.f, 0.f, 0.f, 0.f};

#pragma unroll
    for (int kq = 0; kq < 4; ++kq) {
        bf16x8 a[2], b8[8];
#pragma unroll
        for (int ri = 0; ri < 2; ++ri)
            a[ri] = *(const bf16x8*)&Ap[wv * 32 + ri * 16 + lo][kq * 32 + q4 * 8];
#pragma unroll
        for (int cj = 0; cj < 8; ++cj)
            b8[cj] = *(const bf16x8*)&Bp[cj * 16 + lo][kq * 32 + q4 * 8];
#pragma unroll
        for (int ri = 0; ri < 2; ++ri)
#pragma unroll
            for (int cj = 0; cj < 8; ++cj)
                acc[ri][cj] = __builtin_amdgcn_mfma_f32_16x16x32_bf16(
                    a[ri], b8[cj], acc[ri][cj], 0, 0, 0);
    }

    const int bb = rb >> 3;
    const int s0 = (rb & 7) * 128;
    if (which < 2) {
        bf16* dst = ((which == 0) ? Qh : Kh) + (bb * Hh + h) * Ss * Dd;
#pragma unroll
        for (int ri = 0; ri < 2; ++ri)
#pragma unroll
            for (int cj = 0; cj < 8; ++cj)
#pragma unroll
                for (int r = 0; r < 4; ++r) {
                    int row = wv * 32 + ri * 16 + q4 * 4 + r;
                    int col = cj * 16 + lo;
                    dst[(s0 + row) * Dd + col] = (bf16)acc[ri][cj][r];
                }
    } else {
        bf16* dst = Vt + (bb * Hh + h) * Dd * Ss;
#pragma unroll
        for (int ri = 0; ri < 2; ++ri)
#pragma unroll
            for (int cj = 0; cj < 8; ++cj)
#pragma unroll
                for (int r = 0; r < 4; ++r) {
                    int row = wv * 32 + ri * 16 + q4 * 4 + r;   // d
                    int col = cj * 16 + lo;                     // s-local
                    dst[row * Ss + s0 + col] = (bf16)acc[ri][cj][r];
                }
    }
}

// ---------------------------------------------------------------------------
// K2: streaming attention, P-in-register, DOUBLE-BUFFERED K/V staging.
// block 512 = 8 waves, wave owns 32 qrows -> q-tile 256 rows/block.
// grid (64 bh, 4 qg) = 256 blocks = 1 block/CU, 8 waves/CU.
// One barrier per kt; stage(kt+1) issued right after the barrier so its
// vmcnt drain (next iteration) waits on loads that had a full compute
// phase in flight.  Numeric path identical to R4 (verified).
// ---------------------------------------------------------------------------
__global__ __launch_bounds__(512, 2) void k_attn(
    const bf16* __restrict__ Qh, const bf16* __restrict__ Kh, const bf16* __restrict__ Vt,
    const float* __restrict__ mask, bf16* __restrict__ oc)
{
    const int bh = blockIdx.x;
    const int qg = blockIdx.y;     // 0..3, 256 qrows each
    const int b  = bh >> 3;
    const int h  = bh & 7;
    const int tid  = threadIdx.x;
    const int wv   = tid >> 6;     // 0..7
    const int lane = tid & 63;
    const int lo   = lane & 15;
    const int q4   = lane >> 4;

    __shared__ bf16 KsL[2][64 * 128];   // [buf][key' permuted][d-chunk swizzled]
    __shared__ bf16 VsL[2][128 * 64];   // [buf][d][key-chunk swizzled]
    __shared__ float maskS[1024];       // pre-scaled by log2(e)

    const bf16* Qb = Qh + bh * Ss * Dd;
    const bf16* Kb = Kh + bh * Ss * Dd;
    const bf16* Vb = Vt + bh * Dd * Ss;

    // ---- staging helper (per wave: 2 K-insts + 2 V-insts) ----
    auto stage = [&](int bi, int j0) {
#pragma unroll
        for (int t = 0; t < 2; ++t) {
            int i = wv * 2 + t;                    // 0..15
            int row = i * 4 + (lane >> 4);         // LDS row r' (key')
            int grow = (row & 32) + (((row >> 2) & 3) << 3)
                     + (((row >> 4) & 1) << 2) + (row & 3);
            int g = (lane & 15) ^ (row & 7);
            gl_lds16(Kb + (j0 + grow) * Dd + g * 8, &KsL[bi][i * 512]);
        }
#pragma unroll
        for (int t = 0; t < 2; ++t) {
            int i = wv * 2 + t;
            int row = i * 8 + (lane >> 3);         // d
            int g = (lane & 7) ^ (row & 7);
            gl_lds16(Vb + row * Ss + j0 + g * 8, &VsL[bi][i * 512]);
        }
    };

    stage(0, 0);   // prologue: first tile in flight

#pragma unroll
    for (int t = 0; t < 2; ++t)
        maskS[tid + t * 512] = mask[b * Ss + tid + t * 512] * 1.4426950408889634f;

    // Q fragments (pre-scaled): B-operand of QK.  lane: Q[q0+nt*16+lo][kq*32+q4*8+j]
    const int q0 = qg * 256 + wv * 32;
    bf16x8 qf[2][4];
#pragma unroll
    for (int nt = 0; nt < 2; ++nt)
#pragma unroll
        for (int kq = 0; kq < 4; ++kq)
            qf[nt][kq] = *(const bf16x8*)&Qb[(q0 + nt * 16 + lo) * Dd + kq * 32 + q4 * 8];

    f32x4 accO[8][2];                // O^T[d-tile dm][qrow-tile nt]
#pragma unroll
    for (int dm = 0; dm < 8; ++dm)
#pragma unroll
        for (int nt = 0; nt < 2; ++nt) accO[dm][nt] = f32x4{0.f, 0.f, 0.f, 0.f};
    float lsum[2] = {0.f, 0.f};

    const int sw = lo & 7;   // read-side chunk swizzle key

#pragma unroll 2
    for (int kt = 0; kt < 16; ++kt) {
        const int bi = kt & 1;
        const int j0 = kt * 64;
        __syncthreads();                 // drains vmcnt: buf[bi] (issued last iter) ready
        if (kt < 15) stage(bi ^ 1, j0 + 64);   // async prefetch, full compute phase to land

        // QK: S^T[key'][qrow], 4 key'-tiles x 2 qrow-tiles
        f32x4 sc[4][2];
#pragma unroll
        for (int c = 0; c < 4; ++c)
#pragma unroll
            for (int nt = 0; nt < 2; ++nt) sc[c][nt] = f32x4{0.f, 0.f, 0.f, 0.f};
#pragma unroll
        for (int kq = 0; kq < 4; ++kq) {
            bf16x8 kf[4];
#pragma unroll
            for (int c = 0; c < 4; ++c)
                kf[c] = *(const bf16x8*)&KsL[bi][(c * 16 + lo) * 128 + (((kq << 2) + q4) ^ sw) * 8];
#pragma unroll
            for (int c = 0; c < 4; ++c)
#pragma unroll
                for (int nt = 0; nt < 2; ++nt)
                    sc[c][nt] = __builtin_amdgcn_mfma_f32_16x16x32_bf16(
                        kf[c], qf[nt][kq], sc[c][nt], 0, 0, 0);
        }

        // exp2 + pack straight into PV B-fragments.
        bf16x8 p8[2][2];   // [kb][nt]
#pragma unroll
        for (int kb = 0; kb < 2; ++kb) {
#pragma unroll
            for (int t = 0; t < 2; ++t) {
                const float4 mv = *(const float4*)&maskS[j0 + kb * 32 + q4 * 8 + t * 4];
                const int c = kb * 2 + t;
#pragma unroll
                for (int nt = 0; nt < 2; ++nt) {
                    float e0 = exp2f(sc[c][nt][0] + mv.x);
                    float e1 = exp2f(sc[c][nt][1] + mv.y);
                    float e2 = exp2f(sc[c][nt][2] + mv.z);
                    float e3 = exp2f(sc[c][nt][3] + mv.w);
                    lsum[nt] += (e0 + e1) + (e2 + e3);
                    p8[kb][nt][t * 4 + 0] = (bf16)e0;
                    p8[kb][nt][t * 4 + 1] = (bf16)e1;
                    p8[kb][nt][t * 4 + 2] = (bf16)e2;
                    p8[kb][nt][t * 4 + 3] = (bf16)e3;
                }
            }
        }

        // PV: O^T[d][qrow] += V^T-frag · P-frag
#pragma unroll
        for (int kb = 0; kb < 2; ++kb)
#pragma unroll
            for (int dm = 0; dm < 8; ++dm) {
                bf16x8 vf = *(const bf16x8*)&VsL[bi][(dm * 16 + lo) * 64 + (((kb << 2) + q4) ^ sw) * 8];
#pragma unroll
                for (int nt = 0; nt < 2; ++nt)
                    accO[dm][nt] = __builtin_amdgcn_mfma_f32_16x16x32_bf16(
                        vf, p8[kb][nt], accO[dm][nt], 0, 0, 0);
            }
        // no trailing barrier: next iteration's top barrier protects buf reuse
    }

    // epilogue: row sums (reduce over q4 quads), normalize, store O.
#pragma unroll
    for (int nt = 0; nt < 2; ++nt) {
        float s = lsum[nt];
        s += __shfl_xor(s, 16, 64);
        s += __shfl_xor(s, 32, 64);
        float inv = 1.0f / (s + 1e-12f);
        int sg = q0 + nt * 16 + lo;
        bf16* dst = oc + (b * Ss + sg) * HD + h * 128;
#pragma unroll
        for (int dm = 0; dm < 8; ++dm) {
            bf16x4 o;
#pragma unroll
            for (int r = 0; r < 4; ++r) o[r] = (bf16)(accO[dm][nt][r] * inv);
            *(bf16x4*)&dst[dm * 16 + q4 * 4] = o;
        }
    }
}

// ---------------------------------------------------------------------------
// K3: output projection + bias, streaming (unchanged).
// ---------------------------------------------------------------------------
__global__ __launch_bounds__(256, 4) void k_proj(
    const bf16* __restrict__ oc, const float* __restrict__ Wc,
    const float* __restrict__ bc, float* __restrict__ out)
{
    const int mt   = blockIdx.x;
    const int tid  = threadIdx.x;
    const int wv   = tid >> 6;
    const int lane = tid & 63;
    const int lo   = lane & 15;
    const int q4   = lane >> 4;

    f32x4 acc[2];
    acc[0] = f32x4{0.f, 0.f, 0.f, 0.f};
    acc[1] = f32x4{0.f, 0.f, 0.f, 0.f};

    const bf16* arow = oc + (mt * 16 + lo) * HD + q4 * 8;

    for (int kc = 0; kc < 8; ++kc) {
        const int k0 = kc * 128;
        bf16x8 a[4];
#pragma unroll
        for (int kq = 0; kq < 4; ++kq)
            a[kq] = *(const bf16x8*)&arow[k0 + kq * 32];
#pragma unroll
        for (int cj = 0; cj < 2; ++cj) {
            const int n = wv * 32 + cj * 16 + lo;
#pragma unroll
            for (int kq = 0; kq < 4; ++kq) {
                const float* wp = &Wc[n * HD + k0 + kq * 32 + q4 * 8];
                float4 f0 = *(const float4*)wp;
                float4 f1 = *(const float4*)(wp + 4);
                bf16x8 bfr;
                bfr[0] = (bf16)f0.x; bfr[1] = (bf16)f0.y; bfr[2] = (bf16)f0.z; bfr[3] = (bf16)f0.w;
                bfr[4] = (bf16)f1.x; bfr[5] = (bf16)f1.y; bfr[6] = (bf16)f1.z; bfr[7] = (bf16)f1.w;
                acc[cj] = __builtin_amdgcn_mfma_f32_16x16x32_bf16(
                    a[kq], bfr, acc[cj], 0, 0, 0);
            }
        }
    }

#pragma unroll
    for (int cj = 0; cj < 2; ++cj) {
        int col = wv * 32 + cj * 16 + lo;
        float bias = bc[col];
#pragma unroll
        for (int r = 0; r < 4; ++r) {
            int row = mt * 16 + q4 * 4 + r;
            out[row * Ee + col] = acc[cj][r] + bias;
        }
    }
}

// ---------------------------------------------------------------------------
extern "C" void kernel_launch(void* const* d_in, const int* in_sizes, int n_in,
                              void* d_out, int out_size, void* d_ws, size_t ws_size,
                              hipStream_t stream)
{
    const float* q    = (const float*)d_in[0];
    const float* k    = (const float*)d_in[1];
    const float* v    = (const float*)d_in[2];
    const float* mask = (const float*)d_in[3];
    const float* Wq   = (const float*)d_in[4];
    const float* Wk   = (const float*)d_in[5];
    const float* Wv   = (const float*)d_in[6];
    const float* Wc   = (const float*)d_in[7];
    const float* bc   = (const float*)d_in[8];
    float* out = (float*)d_out;

    constexpr int NBH = Bb * Hh * Ss * Dd;   // 8388608
    bf16* Qh = (bf16*)d_ws;
    bf16* Kh = Qh + NBH;
    bf16* Vt = Kh + NBH;
    bf16* oc = Vt + NBH;
    bf16* Wqb = oc;                          // aliased, dead before k_attn
    bf16* Wkb = Wqb + HD * Ee;
    bf16* Wvb = Wkb + HD * Ee;

    k_cvt<<<dim3(384), 256, 0, stream>>>(Wq, Wk, Wv, Wqb, Wkb, Wvb);
    k_qkv<<<dim3(64, 8, 3), 256, 0, stream>>>(q, k, v, Wqb, Wkb, Wvb, Qh, Kh, Vt);
    k_attn<<<dim3(64, 4), 512, 0, stream>>>(Qh, Kh, Vt, mask, oc);
    k_proj<<<dim3(512), 256, 0, stream>>>(oc, Wc, bc, out);
}